// Round 2
// baseline (5864.080 us; speedup 1.0000x reference)
//
#include <hip/hip_runtime.h>
#include <math.h>

#define CIN 64
#define COFF 27
#define COUT 64

// ---------------- conv3x3 -> 27 channels (offset conv), pad=1 ----------------
// block: 256 threads = 16x16 pixel tile; computes all 27 output channels.
// grid: (W/16, H/16, B)
template<int H, int W>
__global__ __launch_bounds__(256, 2) void conv_off_kernel(
    const float* __restrict__ src,   // B x 64 x H x W
    const float* __restrict__ wgt,   // 27 x 64 x 3 x 3
    const float* __restrict__ bias,  // 27
    float* __restrict__ dst)         // B x 27 x H x W
{
    const int tx = threadIdx.x & 15;
    const int ty = threadIdx.x >> 4;
    const int x0 = blockIdx.x * 16;
    const int y0 = blockIdx.y * 16;
    const int b  = blockIdx.z;

    __shared__ float lds[16][18 * 18];

    float acc[COFF];
#pragma unroll
    for (int o = 0; o < COFF; ++o) acc[o] = bias[o];

    const float* srcb = src + (size_t)b * CIN * H * W;

    for (int c0 = 0; c0 < CIN; c0 += 16) {
        __syncthreads();
        for (int idx = threadIdx.x; idx < 16 * 324; idx += 256) {
            int c  = idx / 324;
            int r  = idx - c * 324;
            int yy = r / 18;
            int xx = r - yy * 18;
            int gy = y0 - 1 + yy;
            int gx = x0 - 1 + xx;
            float v = 0.f;
            if (gy >= 0 && gy < H && gx >= 0 && gx < W)
                v = srcb[((size_t)(c0 + c) * H + gy) * W + gx];
            lds[c][r] = v;
        }
        __syncthreads();
#pragma unroll 1
        for (int c = 0; c < 16; ++c) {
            const float* wc = wgt + (size_t)(c0 + c) * 9;   // + o*576 + t
#pragma unroll
            for (int t = 0; t < 9; ++t) {
                const int ki = t / 3, kj = t % 3;
                float xv = lds[c][(ty + ki) * 18 + (tx + kj)];
#pragma unroll
                for (int o = 0; o < COFF; ++o)
                    acc[o] = fmaf(xv, wc[o * CIN * 9 + t], acc[o]);
            }
        }
    }

    float* dstb = dst + (size_t)b * COFF * H * W;
#pragma unroll
    for (int o = 0; o < COFF; ++o)
        dstb[((size_t)o * H + (y0 + ty)) * W + (x0 + tx)] = acc[o];
}

// ---------------- conv1x1 residual: r = x * rw + rb ----------------
__global__ __launch_bounds__(256, 2) void conv1x1_kernel(
    const float* __restrict__ x,   // B x 64 x 192 x 192
    const float* __restrict__ rw,  // 64 x 64
    const float* __restrict__ rb,  // 64
    float* __restrict__ dst)       // B x 64 x 192 x 192
{
    const int HW = 192 * 192;
    int p  = blockIdx.x * 256 + threadIdx.x;    // over B*HW (exact)
    int b  = p / HW;
    int hw = p - b * HW;
    const float* xb = x + (size_t)b * CIN * HW + hw;

    float acc[COUT];
#pragma unroll
    for (int o = 0; o < COUT; ++o) acc[o] = rb[o];

#pragma unroll 2
    for (int c = 0; c < CIN; ++c) {
        float v = xb[(size_t)c * HW];
#pragma unroll
        for (int o = 0; o < COUT; ++o)
            acc[o] = fmaf(v, rw[o * CIN + c], acc[o]);
    }

    float* db = dst + (size_t)b * COUT * HW + hw;
#pragma unroll
    for (int o = 0; o < COUT; ++o)
        db[(size_t)o * HW] = acc[o];
}

// ---------------- deformable conv v2 (+ elu, optional +upsampled residual) ----------------
// one thread per output pixel, computes all 64 output channels.
// NOTE: every loop touching acc[] MUST be fully unrolled (static indices) or
// acc is demoted to scratch (round-0 bug: VGPR=56, 17% VALUBusy, 2119 us).
template<int H, int W, bool ADD_RES>
__global__ __launch_bounds__(256, 2) void dcn_kernel(
    const float* __restrict__ src,   // B x 64 x H x W
    const float* __restrict__ off,   // B x 27 x H x W
    const float* __restrict__ wgt,   // 64 x 64 x 3 x 3  -> (o,c,k)
    const float* __restrict__ bias,  // 64
    const float* __restrict__ res,   // B x 64 x H/2 x W/2 (if ADD_RES)
    float* __restrict__ dst)         // B x 64 x H x W
{
    const int HW = H * W;
    int p  = blockIdx.x * 256 + threadIdx.x;    // over B*HW (exact)
    int b  = p / HW;
    int hw = p - b * HW;
    int h  = hw / W;
    int w  = hw - h * W;

    float acc[COUT];
#pragma unroll
    for (int o = 0; o < COUT; ++o) acc[o] = bias[o];

    const float* offp = off + (size_t)b * COFF * HW + hw;
    const float* srcb = src + (size_t)b * CIN * HW;

#pragma unroll 1
    for (int k = 0; k < 9; ++k) {
        float dy = offp[(size_t)(2 * k) * HW];
        float dx = offp[(size_t)(2 * k + 1) * HW];
        float mv = offp[(size_t)(18 + k) * HW];
        float m  = 1.f / (1.f + expf(-mv));

        float yf = (float)(h - 1 + k / 3) + dy;
        float xf = (float)(w - 1 + k % 3) + dx;
        float y0f = floorf(yf), x0f = floorf(xf);
        float wy = yf - y0f, wx = xf - x0f;
        int y0 = (int)y0f, x0 = (int)x0f;
        int y1 = y0 + 1,  x1 = x0 + 1;

        float vy0 = (y0 >= 0 && y0 < H) ? 1.f : 0.f;
        float vy1 = (y1 >= 0 && y1 < H) ? 1.f : 0.f;
        float vx0 = (x0 >= 0 && x0 < W) ? 1.f : 0.f;
        float vx1 = (x1 >= 0 && x1 < W) ? 1.f : 0.f;

        float w00 = (1.f - wy) * (1.f - wx) * vy0 * vx0 * m;
        float w01 = (1.f - wy) * wx         * vy0 * vx1 * m;
        float w10 = wy * (1.f - wx)         * vy1 * vx0 * m;
        float w11 = wy * wx                 * vy1 * vx1 * m;

        int y0c = min(max(y0, 0), H - 1), y1c = min(max(y1, 0), H - 1);
        int x0c = min(max(x0, 0), W - 1), x1c = min(max(x1, 0), W - 1);

        const float* p00 = srcb + (size_t)y0c * W + x0c;
        const float* p01 = srcb + (size_t)y0c * W + x1c;
        const float* p10 = srcb + (size_t)y1c * W + x0c;
        const float* p11 = srcb + (size_t)y1c * W + x1c;
        const float* wk  = wgt + k;                        // + (o*64+c)*9

#pragma unroll 4
        for (int c = 0; c < CIN; ++c) {
            float s = w00 * p00[(size_t)c * HW] + w01 * p01[(size_t)c * HW]
                    + w10 * p10[(size_t)c * HW] + w11 * p11[(size_t)c * HW];
#pragma unroll
            for (int o = 0; o < COUT; ++o)
                acc[o] = fmaf(s, wk[(o * CIN + c) * 9], acc[o]);
        }
    }

    float* dstb = dst + (size_t)b * COUT * HW + hw;

    if (ADD_RES) {
        const int Hh = H / 2, Wh = W / 2;
        int iy = h >> 1, ix = w >> 1;
        int oy = (h & 1) ? min(iy + 1, Hh - 1) : max(iy - 1, 0);
        int ox = (w & 1) ? min(ix + 1, Wh - 1) : max(ix - 1, 0);
        const float* rbase = res + (size_t)b * COUT * Hh * Wh + (size_t)iy * Wh;
        const int d_oy = (oy - iy) * Wh;
#pragma unroll
        for (int o = 0; o < COUT; ++o) {
            float v = acc[o];
            v = v > 0.f ? v : (expf(v) - 1.f);
            const float* rp = rbase + (size_t)o * Hh * Wh;
            float r00 = rp[ix], r01 = rp[ox];
            float r10 = rp[d_oy + ix], r11 = rp[d_oy + ox];
            float rv = 0.5625f * r00 + 0.1875f * r01 + 0.1875f * r10 + 0.0625f * r11;
            dstb[(size_t)o * HW] = v + rv;
        }
    } else {
#pragma unroll
        for (int o = 0; o < COUT; ++o) {
            float v = acc[o];
            dstb[(size_t)o * HW] = v > 0.f ? v : (expf(v) - 1.f);
        }
    }
}

// ---------------- bilinear 2x upsample (half-pixel, clamped) ----------------
template<int Hh, int Wh>
__global__ __launch_bounds__(256, 4) void upsample_kernel(
    const float* __restrict__ src,  // B x 64 x Hh x Wh
    float* __restrict__ dst)        // B x 64 x 2Hh x 2Wh
{
    const int H = 2 * Hh, W = 2 * Wh;
    int hw = blockIdx.x * 256 + threadIdx.x;   // over H*W (exact)
    int h = hw / W, w = hw - h * W;
    int c = blockIdx.y, b = blockIdx.z;

    int iy = h >> 1, ix = w >> 1;
    int oy = (h & 1) ? min(iy + 1, Hh - 1) : max(iy - 1, 0);
    int ox = (w & 1) ? min(ix + 1, Wh - 1) : max(ix - 1, 0);

    const float* sp = src + (size_t)(b * COUT + c) * Hh * Wh;
    float r00 = sp[iy * Wh + ix], r01 = sp[iy * Wh + ox];
    float r10 = sp[oy * Wh + ix], r11 = sp[oy * Wh + ox];

    dst[((size_t)(b * COUT + c) * H + h) * W + w] =
        0.5625f * r00 + 0.1875f * r01 + 0.1875f * r10 + 0.0625f * r11;
}

extern "C" void kernel_launch(void* const* d_in, const int* in_sizes, int n_in,
                              void* d_out, int out_size, void* d_ws, size_t ws_size,
                              hipStream_t stream) {
    const float* x   = (const float*)d_in[0];
    const float* ow1 = (const float*)d_in[1];
    const float* ob1 = (const float*)d_in[2];
    const float* w1  = (const float*)d_in[3];
    const float* b1  = (const float*)d_in[4];
    const float* ow2 = (const float*)d_in[5];
    const float* ob2 = (const float*)d_in[6];
    const float* w2  = (const float*)d_in[7];
    const float* b2  = (const float*)d_in[8];
    const float* rw  = (const float*)d_in[9];
    const float* rbv = (const float*)d_in[10];
    float* out = (float*)d_out;

    // workspace layout (floats)
    float* ws   = (float*)d_ws;
    float* off1 = ws;                       //  2*27*192*192 = 1,990,656
    float* h1   = off1 + 1990656;           //  2*64*192*192 = 4,718,592
    float* r    = h1   + 4718592;           //  4,718,592
    float* u    = r    + 4718592;           //  2*64*384*384 = 18,874,368
    float* off2 = u    + 18874368;          //  2*27*384*384 = 7,962,624
    // total 38,264,832 floats = 146 MiB

    conv_off_kernel<192, 192><<<dim3(12, 12, 2), 256, 0, stream>>>(x, ow1, ob1, off1);
    conv1x1_kernel<<<288, 256, 0, stream>>>(x, rw, rbv, r);
    dcn_kernel<192, 192, false><<<288, 256, 0, stream>>>(x, off1, w1, b1, nullptr, h1);
    upsample_kernel<192, 192><<<dim3(576, 64, 2), 256, 0, stream>>>(h1, u);
    conv_off_kernel<384, 384><<<dim3(24, 24, 2), 256, 0, stream>>>(u, ow2, ob2, off2);
    dcn_kernel<384, 384, true><<<1152, 256, 0, stream>>>(u, off2, w2, b2, r, out);
}

// Round 3
// 900.787 us; speedup vs baseline: 6.5100x; 6.5100x over previous
//
#include <hip/hip_runtime.h>
#include <math.h>

typedef unsigned short u16;
typedef __attribute__((ext_vector_type(8))) short bf16x8;
typedef __attribute__((ext_vector_type(4))) float f32x4;

__device__ __forceinline__ u16 f2b(float f) {
    union { float f; unsigned u; } v; v.f = f;
    unsigned r = (v.u + 0x7FFF + ((v.u >> 16) & 1)) >> 16;
    return (u16)r;
}

// ---- weight prep: src fp32 [Nsrc][64][3][3] -> dst bf16 [Npad][576], K = ktap*64 + c ----
__global__ void prep_w_kernel(const float* __restrict__ src, u16* __restrict__ dst,
                              int Nsrc, int Npad) {
    int idx = blockIdx.x * 256 + threadIdx.x;
    if (idx >= Npad * 576) return;
    int n = idx / 576;
    int K = idx - n * 576;
    int ktap = K >> 6;
    int c = K & 63;
    float v = (n < Nsrc) ? src[((size_t)n * 64 + c) * 9 + ktap] : 0.f;
    dst[idx] = f2b(v);
}

// ---------------- MFMA offset conv3x3 (zero-pad): 64 -> 27(pad 32) channels ----------------
// block = 256 thr = 4 waves, tile = 64 consecutive pixels of one row.
template<int H, int W>
__global__ __launch_bounds__(256) void conv_off_mfma(
    const float* __restrict__ src,   // B x 64 x H x W
    const u16*  __restrict__ wb,     // 32 x 576 bf16
    const float* __restrict__ bias,  // 27
    float* __restrict__ dst)         // B x 27 x H x W
{
    const int HW = H * W, SEG = W / 64;
    int blk = blockIdx.x;
    int b = blk / (H * SEG);
    int r2 = blk - b * (H * SEG);
    int h = r2 / SEG;
    int x0 = (r2 - h * SEG) * 64;

    int t = threadIdx.x;
    int px = t & 63;
    int wv = t >> 6;
    int m16 = t & 15;
    int quad = (t & 63) >> 4;

    __shared__ float smem[32 * 67];          // out transpose (8576 B)
    unsigned* stage = (unsigned*)smem;       // [64][33] u32 staging (8448 B)

    const float* srcb = src + (size_t)b * 64 * HW;

    // phase-2 roles: wave -> (oc half, px half)
    const int nh = wv & 1, ph = (wv >> 1) * 32;

    f32x4 acc[2] = {{0,0,0,0},{0,0,0,0}};

    int ki = 0, kj = 0;
    for (int k = 0; k < 9; ++k) {
        int yy = h - 1 + ki;
        bool vy = (yy >= 0) && (yy < H);
        int yc = min(max(yy, 0), H - 1);
        int xx = x0 + px - 1 + kj;
        float fl = (vy && xx >= 0 && xx < W) ? 1.f : 0.f;
        int xc = min(max(xx, 0), W - 1);
        int o = yc * W + xc;

        __syncthreads();
        const float* sc = srcb + (size_t)(wv * 16) * HW + o;
#pragma unroll
        for (int jj = 0; jj < 16; jj += 2) {
            float a0 = fl * sc[(size_t)jj * HW];
            float a1 = fl * sc[(size_t)(jj + 1) * HW];
            stage[px * 33 + wv * 8 + (jj >> 1)] = (unsigned)f2b(a0) | ((unsigned)f2b(a1) << 16);
        }
        __syncthreads();

        const u16* wrow = wb + (size_t)(nh * 16 + m16) * 576 + k * 64 + quad * 8;
        bf16x8 b0 = *(const bf16x8*)(wrow);
        bf16x8 b1 = *(const bf16x8*)(wrow + 32);
#pragma unroll
        for (int pb = 0; pb < 2; ++pb) {
            int base = (ph + pb * 16 + m16) * 33 + quad * 4;
            union { unsigned u[4]; bf16x8 v; } A0, A1;
#pragma unroll
            for (int q = 0; q < 4; ++q) { A0.u[q] = stage[base + q]; A1.u[q] = stage[base + 16 + q]; }
            acc[pb] = __builtin_amdgcn_mfma_f32_16x16x32_bf16(A0.v, b0, acc[pb], 0, 0, 0);
            acc[pb] = __builtin_amdgcn_mfma_f32_16x16x32_bf16(A1.v, b1, acc[pb], 0, 0, 0);
        }
        if (++kj == 3) { kj = 0; ++ki; }
    }

    __syncthreads();
#pragma unroll
    for (int pb = 0; pb < 2; ++pb)
#pragma unroll
        for (int rg = 0; rg < 4; ++rg) {
            int oc = nh * 16 + m16;
            int pp = ph + pb * 16 + quad * 4 + rg;
            smem[oc * 67 + pp] = acc[pb][rg];
        }
    __syncthreads();

    float* dstb = dst + (size_t)b * 27 * HW + (size_t)h * W + x0;
#pragma unroll
    for (int i = 0; i < 7; ++i) {
        int idx = i * 256 + t;
        if (idx < 27 * 64) {
            int oc = idx >> 6, pp = idx & 63;
            dstb[(size_t)oc * HW + pp] = smem[oc * 67 + pp] + bias[oc];
        }
    }
}

// ---------------- MFMA deformable conv v2 (+ELU, optional +upsampled residual) ----------------
template<int H, int W, bool ADD_RES>
__global__ __launch_bounds__(256) void dcn_mfma(
    const float* __restrict__ src,   // B x 64 x H x W
    const float* __restrict__ off,   // B x 27 x H x W
    const u16*  __restrict__ wb,     // 64 x 576 bf16 (oc, ktap*64+c)
    const float* __restrict__ bias,  // 64
    const float* __restrict__ res,   // B x 64 x H/2 x W/2 (if ADD_RES)
    float* __restrict__ dst)         // B x 64 x H x W
{
    const int HW = H * W, SEG = W / 64;
    int blk = blockIdx.x;
    int b = blk / (H * SEG);
    int r2 = blk - b * (H * SEG);
    int h = r2 / SEG;
    int x0 = (r2 - h * SEG) * 64;

    int t = threadIdx.x;
    int px = t & 63;
    int wv = t >> 6;
    int m16 = t & 15;
    int quad = (t & 63) >> 4;

    __shared__ float smem[64 * 67];          // 17152 B; staging aliased below
    unsigned* stage = (unsigned*)smem;       // [64][33] u32

    const float* srcb = src + (size_t)b * 64 * HW;
    const float* offp = off + (size_t)b * 27 * HW + (size_t)h * W + x0 + px;

    f32x4 acc[4] = {{0,0,0,0},{0,0,0,0},{0,0,0,0},{0,0,0,0}};

    int ki = 0, kj = 0;
    for (int k = 0; k < 9; ++k) {
        float dy = offp[(size_t)(2 * k) * HW];
        float dx = offp[(size_t)(2 * k + 1) * HW];
        float mv = offp[(size_t)(18 + k) * HW];
        float mm = 1.f / (1.f + __expf(-mv));

        float yf = (float)(h - 1 + ki) + dy;
        float xf = (float)(x0 + px - 1 + kj) + dx;
        float y0f = floorf(yf), x0f = floorf(xf);
        float wy = yf - y0f, wx = xf - x0f;
        int yi = (int)y0f, xi = (int)x0f;
        float vy0 = (yi >= 0 && yi < H) ? 1.f : 0.f;
        float vy1 = (yi + 1 >= 0 && yi + 1 < H) ? 1.f : 0.f;
        float vx0 = (xi >= 0 && xi < W) ? 1.f : 0.f;
        float vx1 = (xi + 1 >= 0 && xi + 1 < W) ? 1.f : 0.f;
        float w00 = (1.f - wy) * (1.f - wx) * vy0 * vx0 * mm;
        float w01 = (1.f - wy) * wx * vy0 * vx1 * mm;
        float w10 = wy * (1.f - wx) * vy1 * vx0 * mm;
        float w11 = wy * wx * vy1 * vx1 * mm;
        int y0c = min(max(yi, 0), H - 1), y1c = min(max(yi + 1, 0), H - 1);
        int x0c = min(max(xi, 0), W - 1), x1c = min(max(xi + 1, 0), W - 1);
        int o00 = y0c * W + x0c, o01 = y0c * W + x1c;
        int o10 = y1c * W + x0c, o11 = y1c * W + x1c;

        __syncthreads();   // protect stage from previous phase-2 readers
        const float* sc = srcb + (size_t)(wv * 16) * HW;
#pragma unroll
        for (int jj = 0; jj < 16; jj += 2) {
            float a0 = w00 * sc[(size_t)jj * HW + o00] + w01 * sc[(size_t)jj * HW + o01]
                     + w10 * sc[(size_t)jj * HW + o10] + w11 * sc[(size_t)jj * HW + o11];
            float a1 = w00 * sc[(size_t)(jj + 1) * HW + o00] + w01 * sc[(size_t)(jj + 1) * HW + o01]
                     + w10 * sc[(size_t)(jj + 1) * HW + o10] + w11 * sc[(size_t)(jj + 1) * HW + o11];
            stage[px * 33 + wv * 8 + (jj >> 1)] = (unsigned)f2b(a0) | ((unsigned)f2b(a1) << 16);
        }
        __syncthreads();

        const u16* wrow = wb + (size_t)(wv * 16 + m16) * 576 + k * 64 + quad * 8;
        bf16x8 b0 = *(const bf16x8*)(wrow);
        bf16x8 b1 = *(const bf16x8*)(wrow + 32);
#pragma unroll
        for (int pb = 0; pb < 4; ++pb) {
            int base = (pb * 16 + m16) * 33 + quad * 4;
            union { unsigned u[4]; bf16x8 v; } A0, A1;
#pragma unroll
            for (int q = 0; q < 4; ++q) { A0.u[q] = stage[base + q]; A1.u[q] = stage[base + 16 + q]; }
            acc[pb] = __builtin_amdgcn_mfma_f32_16x16x32_bf16(A0.v, b0, acc[pb], 0, 0, 0);
            acc[pb] = __builtin_amdgcn_mfma_f32_16x16x32_bf16(A1.v, b1, acc[pb], 0, 0, 0);
        }
        if (++kj == 3) { kj = 0; ++ki; }
    }

    __syncthreads();
#pragma unroll
    for (int pb = 0; pb < 4; ++pb)
#pragma unroll
        for (int rg = 0; rg < 4; ++rg) {
            int oc = wv * 16 + m16;
            int pp = pb * 16 + quad * 4 + rg;
            smem[oc * 67 + pp] = acc[pb][rg];
        }
    __syncthreads();

    float* dstb = dst + (size_t)b * 64 * HW + (size_t)h * W + x0;
    const int Hh = H / 2, Wh = W / 2;
    int iy = h >> 1;
    int oy = (h & 1) ? min(iy + 1, Hh - 1) : max(iy - 1, 0);
    int doy = (oy - iy) * Wh;
#pragma unroll
    for (int i = 0; i < 16; ++i) {
        int idx = i * 256 + t;
        int oc = idx >> 6, pp = idx & 63;
        float v = smem[oc * 67 + pp] + bias[oc];
        v = v > 0.f ? v : (expf(v) - 1.f);
        if (ADD_RES) {
            int wc = x0 + pp;
            int ix = wc >> 1;
            int ox = (wc & 1) ? min(ix + 1, Wh - 1) : max(ix - 1, 0);
            const float* rp = res + (size_t)(b * 64 + oc) * Hh * Wh + (size_t)iy * Wh;
            float rv = 0.5625f * rp[ix] + 0.1875f * rp[ox]
                     + 0.1875f * rp[doy + ix] + 0.0625f * rp[doy + ox];
            v += rv;
        }
        dstb[(size_t)oc * HW + pp] = v;
    }
}

// ---------------- conv1x1 residual: 16 oc per thread (no spill) ----------------
__global__ __launch_bounds__(256) void conv1x1_kernel(
    const float* __restrict__ x,   // B x 64 x 192 x 192
    const float* __restrict__ rw,  // 64 x 64
    const float* __restrict__ rb,  // 64
    float* __restrict__ dst)       // B x 64 x 192 x 192
{
    const int HW = 192 * 192;
    int p = blockIdx.x * 256 + threadIdx.x;   // over B*HW (exact)
    int g = blockIdx.y;                       // oc group (wave-uniform)
    int b = p / HW;
    int hw = p - b * HW;
    const float* xb = x + (size_t)b * 64 * HW + hw;

    float acc[16];
#pragma unroll
    for (int o = 0; o < 16; ++o) acc[o] = rb[g * 16 + o];

#pragma unroll 4
    for (int c = 0; c < 64; ++c) {
        float v = xb[(size_t)c * HW];
#pragma unroll
        for (int o = 0; o < 16; ++o)
            acc[o] = fmaf(v, rw[(g * 16 + o) * 64 + c], acc[o]);
    }

    float* db = dst + (size_t)b * 64 * HW + (size_t)g * 16 * HW + hw;
#pragma unroll
    for (int o = 0; o < 16; ++o)
        db[(size_t)o * HW] = acc[o];
}

// ---------------- bilinear 2x upsample (half-pixel, clamped) ----------------
template<int Hh, int Wh>
__global__ __launch_bounds__(256) void upsample_kernel(
    const float* __restrict__ src,  // B x 64 x Hh x Wh
    float* __restrict__ dst)        // B x 64 x 2Hh x 2Wh
{
    const int H = 2 * Hh, W = 2 * Wh;
    int hw = blockIdx.x * 256 + threadIdx.x;
    int h = hw / W, w = hw - h * W;
    int c = blockIdx.y, b = blockIdx.z;

    int iy = h >> 1, ix = w >> 1;
    int oy = (h & 1) ? min(iy + 1, Hh - 1) : max(iy - 1, 0);
    int ox = (w & 1) ? min(ix + 1, Wh - 1) : max(ix - 1, 0);

    const float* sp = src + (size_t)(b * 64 + c) * Hh * Wh;
    float r00 = sp[iy * Wh + ix], r01 = sp[iy * Wh + ox];
    float r10 = sp[oy * Wh + ix], r11 = sp[oy * Wh + ox];

    dst[((size_t)(b * 64 + c) * H + h) * W + w] =
        0.5625f * r00 + 0.1875f * r01 + 0.1875f * r10 + 0.0625f * r11;
}

extern "C" void kernel_launch(void* const* d_in, const int* in_sizes, int n_in,
                              void* d_out, int out_size, void* d_ws, size_t ws_size,
                              hipStream_t stream) {
    const float* x   = (const float*)d_in[0];
    const float* ow1 = (const float*)d_in[1];
    const float* ob1 = (const float*)d_in[2];
    const float* w1  = (const float*)d_in[3];
    const float* b1  = (const float*)d_in[4];
    const float* ow2 = (const float*)d_in[5];
    const float* ob2 = (const float*)d_in[6];
    const float* w2  = (const float*)d_in[7];
    const float* b2  = (const float*)d_in[8];
    const float* rw  = (const float*)d_in[9];
    const float* rbv = (const float*)d_in[10];
    float* out = (float*)d_out;

    // workspace layout (floats)
    float* ws   = (float*)d_ws;
    float* off1 = ws;                       //  2*27*192*192 = 1,990,656
    float* h1   = off1 + 1990656;           //  2*64*192*192 = 4,718,592
    float* r    = h1   + 4718592;           //  4,718,592
    float* u    = r    + 4718592;           //  2*64*384*384 = 18,874,368
    float* off2 = u    + 18874368;          //  2*27*384*384 = 7,962,624
    u16* wb1    = (u16*)(off2 + 7962624);   //  64*576 bf16
    u16* wb2    = wb1 + 64 * 576;           //  64*576
    u16* wboff1 = wb2 + 64 * 576;           //  32*576
    u16* wboff2 = wboff1 + 32 * 576;        //  32*576

    prep_w_kernel<<<(64 * 576 + 255) / 256, 256, 0, stream>>>(w1, wb1, 64, 64);
    prep_w_kernel<<<(64 * 576 + 255) / 256, 256, 0, stream>>>(w2, wb2, 64, 64);
    prep_w_kernel<<<(32 * 576 + 255) / 256, 256, 0, stream>>>(ow1, wboff1, 27, 32);
    prep_w_kernel<<<(32 * 576 + 255) / 256, 256, 0, stream>>>(ow2, wboff2, 27, 32);

    conv_off_mfma<192, 192><<<1152, 256, 0, stream>>>(x, wboff1, ob1, off1);
    conv1x1_kernel<<<dim3(288, 4), 256, 0, stream>>>(x, rw, rbv, r);
    dcn_mfma<192, 192, false><<<1152, 256, 0, stream>>>(x, off1, wb1, b1, nullptr, h1);
    upsample_kernel<192, 192><<<dim3(576, 64, 2), 256, 0, stream>>>(h1, u);
    conv_off_mfma<384, 384><<<4608, 256, 0, stream>>>(u, wboff2, ob2, off2);
    dcn_mfma<384, 384, true><<<4608, 256, 0, stream>>>(u, off2, wb2, b2, r, out);
}